// Round 3
// baseline (418.309 us; speedup 1.0000x reference)
//
#include <hip/hip_runtime.h>
#include <stdint.h>

typedef __attribute__((ext_vector_type(4))) float  floatx4;
typedef __attribute__((ext_vector_type(8))) short  short8;
typedef __attribute__((ext_vector_type(8))) __bf16 bf16x8;

__device__ __forceinline__ unsigned short f2bf(float f) {
  unsigned int u = __builtin_bit_cast(unsigned int, f);
  u += 0x7fffu + ((u >> 16) & 1u);   // round-to-nearest-even
  return (unsigned short)(u >> 16);
}

typedef const __attribute__((address_space(1))) void* gptr_t;
typedef __attribute__((address_space(3))) void*       lptr_t;

// ---------------- fused prep: cast_x | transpose_v | prep_u ----------------
__global__ __launch_bounds__(256) void prep_fused(
    const float* __restrict__ X, const float* __restrict__ V,
    const float* __restrict__ U, const float* __restrict__ S,
    unsigned short* __restrict__ Xb, unsigned short* __restrict__ Vt,
    unsigned short* __restrict__ Ub,
    int castBlocks, int transTotal, int transGX, int vrows, int vcols,
    unsigned int rankMask) {
  __shared__ float tile[32][33];
  int bid = blockIdx.x;
  int tid = threadIdx.x;
  if (bid < castBlocks) {
    size_t i = ((size_t)bid * 256 + tid) * 8;
    const floatx4* p = (const floatx4*)(X + i);
    floatx4 a = p[0], b = p[1];
    union { unsigned short us[8]; short8 v; } o;
    o.us[0] = f2bf(a[0]); o.us[1] = f2bf(a[1]); o.us[2] = f2bf(a[2]); o.us[3] = f2bf(a[3]);
    o.us[4] = f2bf(b[0]); o.us[5] = f2bf(b[1]); o.us[6] = f2bf(b[2]); o.us[7] = f2bf(b[3]);
    *(short8*)(Xb + i) = o.v;
  } else if (bid < castBlocks + transTotal) {
    int b  = bid - castBlocks;
    int bx = (b % transGX) * 32;     // rank dim
    int by = (b / transGX) * 32;     // out_h dim
    int tx = tid & 31;
    int ty = tid >> 5;
    for (int i = ty; i < 32; i += 8)
      tile[i][tx] = V[(size_t)(by + i) * vcols + bx + tx];
    __syncthreads();
    for (int i = ty; i < 32; i += 8)
      Vt[(size_t)(bx + i) * vrows + by + tx] = f2bf(tile[tx][i]);
  } else {
    int b = bid - castBlocks - transTotal;
    size_t i = ((size_t)b * 256 + tid) * 4;
    floatx4 u = *(const floatx4*)(U + i);
    floatx4 s = *(const floatx4*)(S + (i & (size_t)rankMask));
    union { unsigned short us[4]; unsigned long long v; } o;
    o.us[0] = f2bf(u[0] * s[0]); o.us[1] = f2bf(u[1] * s[1]);
    o.us[2] = f2bf(u[2] * s[2]); o.us[3] = f2bf(u[3] * s[3]);
    *(unsigned long long*)(Ub + i) = o.v;
  }
}

// ---------------- GEMM1: Yb[M,N] bf16 = A[M,K] @ Bt[N,K]^T ----------------
// BM=128, BN=128, BK=64 (two 32-wide sub-tiles, one barrier pair per 64-K).
// 4 waves 2x2, wave-tile 64x64 (4x4 of 16x16x32 MFMA). Banded swizzle.
__global__ __launch_bounds__(256, 2)
void gemm1_kernel(const unsigned short* __restrict__ A,
                  const unsigned short* __restrict__ Bt,
                  unsigned short* __restrict__ C,
                  int N, int K, int GX) {
  __shared__ unsigned short sA[2][128 * 32];
  __shared__ unsigned short sB[2][128 * 32];

  const int tid  = threadIdx.x;
  const int lane = tid & 63;
  const int wave = tid >> 6;
  const int wm = (wave >> 1) * 64;
  const int wn = (wave & 1) * 64;

  unsigned bid  = blockIdx.x;
  unsigned bw   = 8u * GX;
  unsigned band = bid / bw, rem = bid % bw;
  unsigned by   = band * 8 + (rem & 7u);
  unsigned bx   = rem >> 3;
  const int row0 = by * 128, col0 = bx * 128;

  floatx4 acc[4][4];
#pragma unroll
  for (int i = 0; i < 4; ++i)
#pragma unroll
    for (int j = 0; j < 4; ++j) acc[i][j] = (floatx4){0.f, 0.f, 0.f, 0.f};

  const unsigned short* Ablk = A + (size_t)row0 * K;
  const unsigned short* Bblk = Bt + (size_t)col0 * K;

  const int r0 = tid >> 2, c0 = (tid & 3) * 8;   // j=0 slot; j=1 -> r0+64
  const int ldso0 = (wave * 64) * 8;             // ushort idx within sub-tile
  const int ldso1 = (256 + wave * 64) * 8;
  const int mrow = lane & 15, quad = lane >> 4;

  for (int k0 = 0; k0 < K; k0 += 64) {
#pragma unroll
    for (int t = 0; t < 2; ++t) {
      const int kk = k0 + t * 32;
      __builtin_amdgcn_global_load_lds((gptr_t)(Ablk + (size_t)r0 * K + kk + c0),
                                       (lptr_t)(sA[t] + ldso0), 16, 0, 0);
      __builtin_amdgcn_global_load_lds((gptr_t)(Ablk + (size_t)(r0 + 64) * K + kk + c0),
                                       (lptr_t)(sA[t] + ldso1), 16, 0, 0);
      __builtin_amdgcn_global_load_lds((gptr_t)(Bblk + (size_t)r0 * K + kk + c0),
                                       (lptr_t)(sB[t] + ldso0), 16, 0, 0);
      __builtin_amdgcn_global_load_lds((gptr_t)(Bblk + (size_t)(r0 + 64) * K + kk + c0),
                                       (lptr_t)(sB[t] + ldso1), 16, 0, 0);
    }
    __syncthreads();
#pragma unroll
    for (int t = 0; t < 2; ++t) {
      bf16x8 af[4], bfr[4];
#pragma unroll
      for (int mi = 0; mi < 4; ++mi)
        af[mi] = __builtin_bit_cast(bf16x8,
                  *(const short8*)(sA[t] + (wm + mi * 16 + mrow) * 32 + quad * 8));
#pragma unroll
      for (int ni = 0; ni < 4; ++ni)
        bfr[ni] = __builtin_bit_cast(bf16x8,
                  *(const short8*)(sB[t] + (wn + ni * 16 + mrow) * 32 + quad * 8));
#pragma unroll
      for (int mi = 0; mi < 4; ++mi)
#pragma unroll
        for (int ni = 0; ni < 4; ++ni)
          acc[mi][ni] = __builtin_amdgcn_mfma_f32_16x16x32_bf16(af[mi], bfr[ni],
                                                                acc[mi][ni], 0, 0, 0);
    }
    __syncthreads();
  }

  const int orow = row0 + wm + quad * 4;
  const int ocol = col0 + wn + mrow;
#pragma unroll
  for (int mi = 0; mi < 4; ++mi)
#pragma unroll
    for (int r = 0; r < 4; ++r) {
      size_t rowoff = (size_t)(orow + mi * 16 + r) * N;
#pragma unroll
      for (int ni = 0; ni < 4; ++ni)
        C[rowoff + ocol + ni * 16] = f2bf(acc[mi][ni][r]);
    }
}

// ---------------- GEMM2: C[M,N] fp32 = A[M,K] @ Bt[N,K]^T + bias ----------------
// 256x256 tile, BK=64, 512 threads (8 waves, 2Mx4N, wave-tile 128x64).
// 2-phase-per-K-tile, 2-barriers-per-phase schedule (m201 pattern):
//   P0(mg=0): read A-half0 frags + ALL B frags (16 ds_read_b128), 32 MFMA
//   P1(mg=1): read A-half1 frags (8 ds_read_b128, B reused from regs), 32 MFMA
// Region ledger (certified by each phase's end barrier):
//   after P0: A row-groups {j0,j2} + all B of buf[c] consumed -> P1 stages
//             tile kt+2's {A j0,j2; B j0..3} (6 loads) into buf[c].
//   after P1: A row-groups {j1,j3} consumed -> next P0 stages tile kt+1's
//             {A j1,j3} (2 loads) into buf[c^1].
// vmcnt: uniform vmcnt(8) at phase entry (prologue 6+2+6 reproduces steady
// state); vmcnt(0) only in the last two P1 phases. XOR slot-swizzle unchanged.
__global__ __launch_bounds__(512, 2)
void gemm2_kernel(const unsigned short* __restrict__ A,
                  const unsigned short* __restrict__ Bt,
                  float* __restrict__ C, const float* __restrict__ bias,
                  int N, int K, int GX) {
  __shared__ unsigned short sA[2][256 * 64];   // 64 KiB
  __shared__ unsigned short sB[2][256 * 64];   // 64 KiB

  const int tid  = threadIdx.x;
  const int lane = tid & 63;
  const int wave = tid >> 6;
  const int wm = (wave >> 2) * 128;            // 2 wave rows
  const int wn = (wave & 3) * 64;              // 4 wave cols

  unsigned bid  = blockIdx.x;
  unsigned bw   = 8u * GX;
  unsigned band = bid / bw, rem = bid % bw;
  unsigned by   = band * 8 + (rem & 7u);
  unsigned bx   = rem >> 3;
  const int row0 = by * 256, col0 = bx * 256;

  floatx4 acc[8][4];
#pragma unroll
  for (int i = 0; i < 8; ++i)
#pragma unroll
    for (int j = 0; j < 4; ++j) acc[i][j] = (floatx4){0.f, 0.f, 0.f, 0.f};

  // Staging: LDS dest linear (row = j*64 + wave*8 + lane/8, slot lane&7);
  // global source embeds inverse swizzle: slot = (lane&7) ^ (row&7).
  const int srow = wave * 8 + (lane >> 3);
  const int ssl  = (lane & 7) ^ (lane >> 3);
  const unsigned short* Ag = A  + (size_t)(row0 + srow) * K + ssl * 8;
  const unsigned short* Bg = Bt + (size_t)(col0 + srow) * K + ssl * 8;
  const int ldsw = (wave * 8) * 64;            // wave-uniform ushort offset

  // Fragment reads: phys 16B slot = (ks*4+quad) ^ (row&7), row&7 == mrow&7.
  const int mrow = lane & 15, quad = lane >> 4;
  const int sw   = mrow & 7;
  const int pko0 = ((quad    ) ^ sw) << 3;     // ks=0, ushort offset
  const int pko1 = ((quad + 4) ^ sw) << 3;     // ks=1

  const int NKT = K >> 6;                      // 16 for K=1024

  // A row-groups {j1,j3} of tile at KOFF -> buf BUF (2 loads)
#define STAGE_RA1(BUF, KOFF)                                                   \
  {                                                                            \
    const unsigned short* As_ = Ag + (KOFF);                                   \
    unsigned short* dA_ = &sA[(BUF)][0] + ldsw;                                \
    __builtin_amdgcn_global_load_lds((gptr_t)(As_ + (size_t)64 * K),           \
                                     (lptr_t)(dA_ + 4096), 16, 0, 0);          \
    __builtin_amdgcn_global_load_lds((gptr_t)(As_ + (size_t)192 * K),          \
                                     (lptr_t)(dA_ + 12288), 16, 0, 0);         \
  }

  // A row-groups {j0,j2} + all B of tile at KOFF -> buf BUF (6 loads)
#define STAGE_RA0RB(BUF, KOFF)                                                 \
  {                                                                            \
    const unsigned short* As_ = Ag + (KOFF);                                   \
    const unsigned short* Bs_ = Bg + (KOFF);                                   \
    unsigned short* dA_ = &sA[(BUF)][0] + ldsw;                                \
    unsigned short* dB_ = &sB[(BUF)][0] + ldsw;                                \
    __builtin_amdgcn_global_load_lds((gptr_t)(As_),                            \
                                     (lptr_t)(dA_), 16, 0, 0);                 \
    __builtin_amdgcn_global_load_lds((gptr_t)(As_ + (size_t)128 * K),          \
                                     (lptr_t)(dA_ + 8192), 16, 0, 0);          \
    _Pragma("unroll")                                                          \
    for (int j_ = 0; j_ < 4; ++j_)                                             \
      __builtin_amdgcn_global_load_lds((gptr_t)(Bs_ + (size_t)j_ * 64 * K),    \
                                       (lptr_t)(dB_ + j_ * 4096), 16, 0, 0);   \
  }

  // Prologue: t0 RA0RB (6), t0 RA1 (2), t1 RA0RB (6)  -> 14 in flight.
  STAGE_RA0RB(0, 0);
  STAGE_RA1 (0, 0);
  STAGE_RA0RB(1, 64);

  for (int kt = 0; kt < NKT; ++kt) {
    const int c = kt & 1;
    const unsigned short* bA = &sA[c][0];
    const unsigned short* bB = &sB[c][0];

    // ================= P0 (mg = 0) =================
    asm volatile("s_waitcnt vmcnt(8)" ::: "memory");   // t_kt RA0+RB landed
    __builtin_amdgcn_sched_barrier(0);
    if (kt + 1 < NKT) STAGE_RA1(c ^ 1, (kt + 1) * 64); // 2 loads
    bf16x8 b0[4][2], a0[4][2];
#pragma unroll
    for (int ni = 0; ni < 4; ++ni) {
      const unsigned short* p = bB + (wn + ni * 16 + mrow) * 64;
      b0[ni][0] = __builtin_bit_cast(bf16x8, *(const short8*)(p + pko0));
      b0[ni][1] = __builtin_bit_cast(bf16x8, *(const short8*)(p + pko1));
    }
#pragma unroll
    for (int i = 0; i < 4; ++i) {
      const unsigned short* p = bA + (wm + i * 16 + mrow) * 64;
      a0[i][0] = __builtin_bit_cast(bf16x8, *(const short8*)(p + pko0));
      a0[i][1] = __builtin_bit_cast(bf16x8, *(const short8*)(p + pko1));
    }
    __builtin_amdgcn_sched_barrier(0);
    __builtin_amdgcn_s_barrier();
    asm volatile("s_waitcnt lgkmcnt(0)" ::: "memory");
    __builtin_amdgcn_sched_barrier(0);
    __builtin_amdgcn_s_setprio(1);
#pragma unroll
    for (int ks = 0; ks < 2; ++ks)
#pragma unroll
      for (int i = 0; i < 4; ++i)
#pragma unroll
        for (int ni = 0; ni < 4; ++ni)
          acc[i][ni] = __builtin_amdgcn_mfma_f32_16x16x32_bf16(a0[i][ks], b0[ni][ks],
                                                               acc[i][ni], 0, 0, 0);
    __builtin_amdgcn_s_setprio(0);
    __builtin_amdgcn_s_barrier();   // certifies: RA0+RB of buf[c] consumed

    // ================= P1 (mg = 1) =================
    if (kt + 2 < NKT) {
      asm volatile("s_waitcnt vmcnt(8)" ::: "memory"); // t_kt RA1 landed
    } else {
      asm volatile("s_waitcnt vmcnt(0)" ::: "memory");
    }
    __builtin_amdgcn_sched_barrier(0);
    if (kt + 2 < NKT) STAGE_RA0RB(c, (kt + 2) * 64);   // 6 loads
    bf16x8 a1[4][2];
#pragma unroll
    for (int i = 0; i < 4; ++i) {
      const unsigned short* p = bA + (wm + 64 + i * 16 + mrow) * 64;
      a1[i][0] = __builtin_bit_cast(bf16x8, *(const short8*)(p + pko0));
      a1[i][1] = __builtin_bit_cast(bf16x8, *(const short8*)(p + pko1));
    }
    __builtin_amdgcn_sched_barrier(0);
    __builtin_amdgcn_s_barrier();
    asm volatile("s_waitcnt lgkmcnt(0)" ::: "memory");
    __builtin_amdgcn_sched_barrier(0);
    __builtin_amdgcn_s_setprio(1);
#pragma unroll
    for (int ks = 0; ks < 2; ++ks)
#pragma unroll
      for (int i = 0; i < 4; ++i)
#pragma unroll
        for (int ni = 0; ni < 4; ++ni)
          acc[4 + i][ni] = __builtin_amdgcn_mfma_f32_16x16x32_bf16(a1[i][ks], b0[ni][ks],
                                                                   acc[4 + i][ni], 0, 0, 0);
    __builtin_amdgcn_s_setprio(0);
    __builtin_amdgcn_s_barrier();   // certifies: RA1 of buf[c] consumed
  }
#undef STAGE_RA1
#undef STAGE_RA0RB

  const int orow = row0 + wm + quad * 4;
  const int ocol = col0 + wn + mrow;
  float bv[4];
#pragma unroll
  for (int ni = 0; ni < 4; ++ni) bv[ni] = bias[ocol + ni * 16];
#pragma unroll
  for (int mi = 0; mi < 8; ++mi)
#pragma unroll
    for (int r = 0; r < 4; ++r) {
      size_t rowoff = (size_t)(orow + mi * 16 + r) * N;
#pragma unroll
      for (int ni = 0; ni < 4; ++ni)
        C[rowoff + ocol + ni * 16] = acc[mi][ni][r] + bv[ni];
    }
}

extern "C" void kernel_launch(void* const* d_in, const int* in_sizes, int n_in,
                              void* d_out, int out_size, void* d_ws, size_t ws_size,
                              hipStream_t stream) {
  const float* x    = (const float*)d_in[0];  // [B*T, OUT_H]
  const float* U    = (const float*)d_in[1];  // [IN_H, RANK]
  const float* S    = (const float*)d_in[2];  // [RANK]
  const float* V    = (const float*)d_in[3];  // [OUT_H, RANK]
  const float* bias = (const float*)d_in[4];  // [IN_H]

  const int RANK = in_sizes[2];               // 1024
  const int INH  = in_sizes[4];               // 4096
  const int OUTH = in_sizes[3] / RANK;        // 4096
  const int M    = in_sizes[0] / OUTH;        // 8192

  unsigned short* Xb = (unsigned short*)d_ws;
  unsigned short* Vt = Xb + (size_t)M * OUTH;
  unsigned short* Ub = Vt + (size_t)RANK * OUTH;
  unsigned short* Yb = Ub + (size_t)INH * RANK;

  const int castBlocks = (int)(((size_t)M * OUTH) / 2048);
  const int transGX    = RANK / 32;
  const int transTotal = transGX * (OUTH / 32);
  const int prepUBlk   = (int)(((size_t)INH * RANK) / 1024);
  prep_fused<<<castBlocks + transTotal + prepUBlk, 256, 0, stream>>>(
      x, V, U, S, Xb, Vt, Ub, castBlocks, transTotal, transGX, OUTH, RANK,
      (unsigned)(RANK - 1));

  // GEMM1: grid = (M/128)*(RANK/128) = 64*8 = 512, GX=8
  gemm1_kernel<<<(M / 128) * (RANK / 128), 256, 0, stream>>>(
      Xb, Vt, Yb, RANK, OUTH, RANK / 128);

  // GEMM2: 256x256 tiles -> grid = (M/256)*(INH/256) = 32*16 = 512, GX=16
  gemm2_kernel<<<(M / 256) * (INH / 256), 512, 0, stream>>>(
      Yb, Ub, (float*)d_out, bias, INH, RANK, INH / 256);
}

// Round 4
// 391.445 us; speedup vs baseline: 1.0686x; 1.0686x over previous
//
#include <hip/hip_runtime.h>
#include <stdint.h>

typedef __attribute__((ext_vector_type(4))) float  floatx4;
typedef __attribute__((ext_vector_type(8))) short  short8;
typedef __attribute__((ext_vector_type(8))) __bf16 bf16x8;

__device__ __forceinline__ unsigned short f2bf(float f) {
  unsigned int u = __builtin_bit_cast(unsigned int, f);
  u += 0x7fffu + ((u >> 16) & 1u);   // round-to-nearest-even
  return (unsigned short)(u >> 16);
}

typedef const __attribute__((address_space(1))) void* gptr_t;
typedef __attribute__((address_space(3))) void*       lptr_t;

// ---------------- fused prep: cast_x | transpose_v | prep_u ----------------
__global__ __launch_bounds__(256) void prep_fused(
    const float* __restrict__ X, const float* __restrict__ V,
    const float* __restrict__ U, const float* __restrict__ S,
    unsigned short* __restrict__ Xb, unsigned short* __restrict__ Vt,
    unsigned short* __restrict__ Ub,
    int castBlocks, int transTotal, int transGX, int vrows, int vcols,
    unsigned int rankMask) {
  __shared__ float tile[32][33];
  int bid = blockIdx.x;
  int tid = threadIdx.x;
  if (bid < castBlocks) {
    size_t i = ((size_t)bid * 256 + tid) * 8;
    const floatx4* p = (const floatx4*)(X + i);
    floatx4 a = p[0], b = p[1];
    union { unsigned short us[8]; short8 v; } o;
    o.us[0] = f2bf(a[0]); o.us[1] = f2bf(a[1]); o.us[2] = f2bf(a[2]); o.us[3] = f2bf(a[3]);
    o.us[4] = f2bf(b[0]); o.us[5] = f2bf(b[1]); o.us[6] = f2bf(b[2]); o.us[7] = f2bf(b[3]);
    *(short8*)(Xb + i) = o.v;
  } else if (bid < castBlocks + transTotal) {
    int b  = bid - castBlocks;
    int bx = (b % transGX) * 32;     // rank dim
    int by = (b / transGX) * 32;     // out_h dim
    int tx = tid & 31;
    int ty = tid >> 5;
    for (int i = ty; i < 32; i += 8)
      tile[i][tx] = V[(size_t)(by + i) * vcols + bx + tx];
    __syncthreads();
    for (int i = ty; i < 32; i += 8)
      Vt[(size_t)(bx + i) * vrows + by + tx] = f2bf(tile[tx][i]);
  } else {
    int b = bid - castBlocks - transTotal;
    size_t i = ((size_t)b * 256 + tid) * 4;
    floatx4 u = *(const floatx4*)(U + i);
    floatx4 s = *(const floatx4*)(S + (i & (size_t)rankMask));
    union { unsigned short us[4]; unsigned long long v; } o;
    o.us[0] = f2bf(u[0] * s[0]); o.us[1] = f2bf(u[1] * s[1]);
    o.us[2] = f2bf(u[2] * s[2]); o.us[3] = f2bf(u[3] * s[3]);
    *(unsigned long long*)(Ub + i) = o.v;
  }
}

// ---------------- GEMM1: Yb[M,N] bf16 = A[M,K] @ Bt[N,K]^T ----------------
// BM=128, BN=128, BK=64, 256 threads (4 waves 2x2, wave-tile 64x64 = 4x4 of
// 16x16x32). Same verified template as gemm2: counted-vmcnt double buffer
// (stage 8 loads/tile/thread, steady-state vmcnt(8), vmcnt(0) only at tail),
// XOR slot-swizzle (phys 16B slot = slot ^ (row&7), inverse applied on the
// per-lane global source so the global_load_lds dest stays linear), raw
// s_barrier, setprio around MFMA.
__global__ __launch_bounds__(256, 2)
void gemm1_kernel(const unsigned short* __restrict__ A,
                  const unsigned short* __restrict__ Bt,
                  unsigned short* __restrict__ C,
                  int N, int K, int GX) {
  __shared__ unsigned short sA[2][128 * 64];   // 16 KiB per buf
  __shared__ unsigned short sB[2][128 * 64];

  const int tid  = threadIdx.x;
  const int lane = tid & 63;
  const int wave = tid >> 6;
  const int wm = (wave >> 1) * 64;
  const int wn = (wave & 1) * 64;

  unsigned bid  = blockIdx.x;
  unsigned bw   = 8u * GX;
  unsigned band = bid / bw, rem = bid % bw;
  unsigned by   = band * 8 + (rem & 7u);
  unsigned bx   = rem >> 3;
  const int row0 = by * 128, col0 = bx * 128;

  floatx4 acc[4][4];
#pragma unroll
  for (int i = 0; i < 4; ++i)
#pragma unroll
    for (int j = 0; j < 4; ++j) acc[i][j] = (floatx4){0.f, 0.f, 0.f, 0.f};

  // Staging: LDS dest linear (row = j*32 + wave*8 + lane/8, slot lane&7);
  // global source embeds inverse swizzle: slot = (lane&7) ^ (row&7),
  // row&7 == lane>>3 (wave*8 and j*32 are 0 mod 8).
  const int srow = wave * 8 + (lane >> 3);     // [0,32)
  const int ssl  = (lane & 7) ^ (lane >> 3);
  const unsigned short* Ag = A  + (size_t)(row0 + srow) * K + ssl * 8;
  const unsigned short* Bg = Bt + (size_t)(col0 + srow) * K + ssl * 8;
  const int ldsw = (wave * 8) * 64;            // wave-uniform ushort offset

  // Fragment reads: phys 16B slot = (ks*4+quad) ^ (row&7), row&7 == mrow&7.
  const int mrow = lane & 15, quad = lane >> 4;
  const int sw   = mrow & 7;
  const int pko0 = ((quad    ) ^ sw) << 3;     // ks=0, ushort offset
  const int pko1 = ((quad + 4) ^ sw) << 3;     // ks=1

  const int NKT = K >> 6;                      // 64 for K=4096

  // 8 global_load_lds per K-tile per thread (4 A + 4 B), 32 rows per j-step.
#define STAGE_G1(KOFF, BUF)                                                    \
  {                                                                            \
    const unsigned short* As_ = Ag + (KOFF);                                   \
    const unsigned short* Bs_ = Bg + (KOFF);                                   \
    unsigned short* dA_ = &sA[(BUF)][0] + ldsw;                                \
    unsigned short* dB_ = &sB[(BUF)][0] + ldsw;                                \
    _Pragma("unroll")                                                          \
    for (int j_ = 0; j_ < 4; ++j_) {                                           \
      __builtin_amdgcn_global_load_lds((gptr_t)(As_ + (size_t)j_ * 32 * K),    \
                                       (lptr_t)(dA_ + j_ * 2048), 16, 0, 0);   \
      __builtin_amdgcn_global_load_lds((gptr_t)(Bs_ + (size_t)j_ * 32 * K),    \
                                       (lptr_t)(dB_ + j_ * 2048), 16, 0, 0);   \
    }                                                                          \
  }

  // Prologue: T0 -> buf0, T1 -> buf1; wait T0 landed (T1's 8 stay in flight).
  STAGE_G1(0, 0);
  STAGE_G1(64, 1);
  asm volatile("s_waitcnt vmcnt(8)" ::: "memory");
  __builtin_amdgcn_s_barrier();

  int cur = 0;
  for (int kt = 0; kt < NKT; ++kt) {
    const unsigned short* bA = &sA[cur][0];
    const unsigned short* bB = &sB[cur][0];
#pragma unroll
    for (int ks = 0; ks < 2; ++ks) {
      const int pko = ks ? pko1 : pko0;
      bf16x8 bfr[4], af[4];
#pragma unroll
      for (int ni = 0; ni < 4; ++ni)
        bfr[ni] = __builtin_bit_cast(bf16x8,
                    *(const short8*)(bB + (wn + ni * 16 + mrow) * 64 + pko));
#pragma unroll
      for (int mi = 0; mi < 4; ++mi)
        af[mi] = __builtin_bit_cast(bf16x8,
                    *(const short8*)(bA + (wm + mi * 16 + mrow) * 64 + pko));
      __builtin_amdgcn_s_setprio(1);
#pragma unroll
      for (int mi = 0; mi < 4; ++mi)
#pragma unroll
        for (int ni = 0; ni < 4; ++ni)
          acc[mi][ni] = __builtin_amdgcn_mfma_f32_16x16x32_bf16(af[mi], bfr[ni],
                                                                acc[mi][ni], 0, 0, 0);
      __builtin_amdgcn_s_setprio(0);
    }
    // All reads of buf[cur] complete -> barrier -> safe to restage buf[cur].
    asm volatile("s_waitcnt lgkmcnt(0)" ::: "memory");
    __builtin_amdgcn_sched_barrier(0);
    __builtin_amdgcn_s_barrier();
    __builtin_amdgcn_sched_barrier(0);
    if (kt + 2 < NKT) {
      STAGE_G1((kt + 2) * 64, cur);
      // wait for T(kt+1)'s 8 loads; T(kt+2)'s 8 remain in flight
      asm volatile("s_waitcnt vmcnt(8)" ::: "memory");
      __builtin_amdgcn_s_barrier();
    } else if (kt + 1 < NKT) {
      asm volatile("s_waitcnt vmcnt(0)" ::: "memory");
      __builtin_amdgcn_s_barrier();
    }
    cur ^= 1;
  }
#undef STAGE_G1

  const int orow = row0 + wm + quad * 4;
  const int ocol = col0 + wn + mrow;
#pragma unroll
  for (int mi = 0; mi < 4; ++mi)
#pragma unroll
    for (int r = 0; r < 4; ++r) {
      size_t rowoff = (size_t)(orow + mi * 16 + r) * N;
#pragma unroll
      for (int ni = 0; ni < 4; ++ni)
        C[rowoff + ocol + ni * 16] = f2bf(acc[mi][ni][r]);
    }
}

// ---------------- GEMM2: C[M,N] fp32 = A[M,K] @ Bt[N,K]^T + bias ----------------
// 256x256 tile, BK=64, 512 threads (8 waves, 2Mx4N, wave-tile 128x64 = 8x4 of
// 16x16x32). Counted-vmcnt 2-K-tile pipeline, XOR slot-swizzle, setprio.
// (Verified round-2 version: 88.4 us, SQ_LDS_BANK_CONFLICT = 0.)
__global__ __launch_bounds__(512, 2)
void gemm2_kernel(const unsigned short* __restrict__ A,
                  const unsigned short* __restrict__ Bt,
                  float* __restrict__ C, const float* __restrict__ bias,
                  int N, int K, int GX) {
  __shared__ unsigned short sA[2][256 * 64];   // 64 KiB
  __shared__ unsigned short sB[2][256 * 64];   // 64 KiB

  const int tid  = threadIdx.x;
  const int lane = tid & 63;
  const int wave = tid >> 6;
  const int wm = (wave >> 2) * 128;            // 2 wave rows
  const int wn = (wave & 3) * 64;              // 4 wave cols

  unsigned bid  = blockIdx.x;
  unsigned bw   = 8u * GX;
  unsigned band = bid / bw, rem = bid % bw;
  unsigned by   = band * 8 + (rem & 7u);
  unsigned bx   = rem >> 3;
  const int row0 = by * 256, col0 = bx * 256;

  floatx4 acc[8][4];
#pragma unroll
  for (int i = 0; i < 8; ++i)
#pragma unroll
    for (int j = 0; j < 4; ++j) acc[i][j] = (floatx4){0.f, 0.f, 0.f, 0.f};

  // Staging: LDS dest linear (row = j*64 + wave*8 + lane/8, slot lane&7);
  // global source embeds inverse swizzle: slot = (lane&7) ^ (row&7).
  const int srow = wave * 8 + (lane >> 3);
  const int ssl  = (lane & 7) ^ (lane >> 3);
  const unsigned short* Ag = A  + (size_t)(row0 + srow) * K + ssl * 8;
  const unsigned short* Bg = Bt + (size_t)(col0 + srow) * K + ssl * 8;
  const int ldsw = (wave * 8) * 64;            // wave-uniform ushort offset

  // Fragment reads: phys 16B slot = (ks*4+quad) ^ (row&7), row&7 == mrow&7.
  const int mrow = lane & 15, quad = lane >> 4;
  const int sw = mrow & 7;
  const int paof[2] = { (wm + mrow) * 64 + ((quad ^ sw) << 3),
                        (wm + mrow) * 64 + (((quad + 4) ^ sw) << 3) };
  const int pbof[2] = { (wn + mrow) * 64 + ((quad ^ sw) << 3),
                        (wn + mrow) * 64 + (((quad + 4) ^ sw) << 3) };

  const int NKT = K >> 6;                      // 16 for K=1024

  // 8 global_load_lds per K-tile per thread (4 A + 4 B).
#define STAGE_G2(KOFF, BUF)                                                    \
  {                                                                            \
    const unsigned short* As_ = Ag + (KOFF);                                   \
    const unsigned short* Bs_ = Bg + (KOFF);                                   \
    unsigned short* dA_ = &sA[(BUF)][0] + ldsw;                                \
    unsigned short* dB_ = &sB[(BUF)][0] + ldsw;                                \
    _Pragma("unroll")                                                          \
    for (int j_ = 0; j_ < 4; ++j_) {                                           \
      __builtin_amdgcn_global_load_lds((gptr_t)(As_ + (size_t)j_ * 64 * K),    \
                                       (lptr_t)(dA_ + j_ * 4096), 16, 0, 0);   \
      __builtin_amdgcn_global_load_lds((gptr_t)(Bs_ + (size_t)j_ * 64 * K),    \
                                       (lptr_t)(dB_ + j_ * 4096), 16, 0, 0);   \
    }                                                                          \
  }

  // Prologue: T0 -> buf0, T1 -> buf1; wait T0 landed (T1's 8 stay in flight).
  STAGE_G2(0, 0);
  STAGE_G2(64, 1);
  asm volatile("s_waitcnt vmcnt(8)" ::: "memory");
  __builtin_amdgcn_s_barrier();

  int cur = 0;
  for (int kt = 0; kt < NKT; ++kt) {
    const unsigned short* bA = &sA[cur][0];
    const unsigned short* bB = &sB[cur][0];
#pragma unroll
    for (int ks = 0; ks < 2; ++ks) {
      bf16x8 bfr[4], af[8];
#pragma unroll
      for (int ni = 0; ni < 4; ++ni)
        bfr[ni] = __builtin_bit_cast(bf16x8,
                    *(const short8*)(bB + pbof[ks] + ni * 1024));
#pragma unroll
      for (int mi = 0; mi < 8; ++mi)
        af[mi] = __builtin_bit_cast(bf16x8,
                    *(const short8*)(bA + paof[ks] + mi * 1024));
      __builtin_amdgcn_s_setprio(1);
#pragma unroll
      for (int mi = 0; mi < 8; ++mi)
#pragma unroll
        for (int ni = 0; ni < 4; ++ni)
          acc[mi][ni] = __builtin_amdgcn_mfma_f32_16x16x32_bf16(af[mi], bfr[ni],
                                                                acc[mi][ni], 0, 0, 0);
      __builtin_amdgcn_s_setprio(0);
    }
    // All reads of buf[cur] complete -> barrier -> safe to restage buf[cur].
    asm volatile("s_waitcnt lgkmcnt(0)" ::: "memory");
    __builtin_amdgcn_sched_barrier(0);
    __builtin_amdgcn_s_barrier();
    __builtin_amdgcn_sched_barrier(0);
    if (kt + 2 < NKT) {
      STAGE_G2((kt + 2) * 64, cur);
      // wait for T(kt+1)'s 8 loads; T(kt+2)'s 8 remain in flight
      asm volatile("s_waitcnt vmcnt(8)" ::: "memory");
      __builtin_amdgcn_s_barrier();
    } else if (kt + 1 < NKT) {
      asm volatile("s_waitcnt vmcnt(0)" ::: "memory");
      __builtin_amdgcn_s_barrier();
    }
    cur ^= 1;
  }
#undef STAGE_G2

  const int orow = row0 + wm + quad * 4;
  const int ocol = col0 + wn + mrow;
  float bv[4];
#pragma unroll
  for (int ni = 0; ni < 4; ++ni) bv[ni] = bias[ocol + ni * 16];
#pragma unroll
  for (int mi = 0; mi < 8; ++mi)
#pragma unroll
    for (int r = 0; r < 4; ++r) {
      size_t rowoff = (size_t)(orow + mi * 16 + r) * N;
#pragma unroll
      for (int ni = 0; ni < 4; ++ni)
        C[rowoff + ocol + ni * 16] = acc[mi][ni][r] + bv[ni];
    }
}

extern "C" void kernel_launch(void* const* d_in, const int* in_sizes, int n_in,
                              void* d_out, int out_size, void* d_ws, size_t ws_size,
                              hipStream_t stream) {
  const float* x    = (const float*)d_in[0];  // [B*T, OUT_H]
  const float* U    = (const float*)d_in[1];  // [IN_H, RANK]
  const float* S    = (const float*)d_in[2];  // [RANK]
  const float* V    = (const float*)d_in[3];  // [OUT_H, RANK]
  const float* bias = (const float*)d_in[4];  // [IN_H]

  const int RANK = in_sizes[2];               // 1024
  const int INH  = in_sizes[4];               // 4096
  const int OUTH = in_sizes[3] / RANK;        // 4096
  const int M    = in_sizes[0] / OUTH;        // 8192

  unsigned short* Xb = (unsigned short*)d_ws;
  unsigned short* Vt = Xb + (size_t)M * OUTH;
  unsigned short* Ub = Vt + (size_t)RANK * OUTH;
  unsigned short* Yb = Ub + (size_t)INH * RANK;

  const int castBlocks = (int)(((size_t)M * OUTH) / 2048);
  const int transGX    = RANK / 32;
  const int transTotal = transGX * (OUTH / 32);
  const int prepUBlk   = (int)(((size_t)INH * RANK) / 1024);
  prep_fused<<<castBlocks + transTotal + prepUBlk, 256, 0, stream>>>(
      x, V, U, S, Xb, Vt, Ub, castBlocks, transTotal, transGX, OUTH, RANK,
      (unsigned)(RANK - 1));

  // GEMM1: grid = (M/128)*(RANK/128) = 64*8 = 512, GX=8
  gemm1_kernel<<<(M / 128) * (RANK / 128), 256, 0, stream>>>(
      Xb, Vt, Yb, RANK, OUTH, RANK / 128);

  // GEMM2: 256x256 tiles -> grid = (M/256)*(INH/256) = 32*16 = 512, GX=16
  gemm2_kernel<<<(M / 256) * (INH / 256), 512, 0, stream>>>(
      Yb, Ub, (float*)d_out, bias, INH, RANK, INH / 256);
}